// Round 5
// baseline (200.614 us; speedup 1.0000x reference)
//
#include <hip/hip_runtime.h>

#define CC 256
#define NN 1024
#define CN (CC*NN)

typedef __attribute__((ext_vector_type(8))) short short8;
typedef __attribute__((ext_vector_type(8))) unsigned short u16x8;
typedef __attribute__((ext_vector_type(4))) float f32x4;

__device__ __forceinline__ unsigned short f2bf(float x) {
  unsigned u = __float_as_uint(x);
  u = u + 0x7fffu + ((u >> 16) & 1u);
  return (unsigned short)(u >> 16);
}
__device__ __forceinline__ float bf2f(unsigned short b) {
  return __uint_as_float(((unsigned)b) << 16);
}
__device__ __forceinline__ void gload_lds16(const unsigned short* g, unsigned short* l) {
  __builtin_amdgcn_global_load_lds(
      (const __attribute__((address_space(1))) unsigned short*)g,
      (__attribute__((address_space(3))) unsigned short*)l, 16, 0, 0);
}

// ---------- prep: weight convert + x-transpose + q/k proj + xv proj + passthrough copy ----------
__global__ __launch_bounds__(256) void prep_kernel(
    const float* __restrict__ x, const float* __restrict__ Wq,
    const float* __restrict__ Wk, const float* __restrict__ Wv,
    const float* __restrict__ bv,
    const float4* __restrict__ W1, const float4* __restrict__ W2,
    unsigned short* __restrict__ w1_bf, unsigned short* __restrict__ w2_bf,
    unsigned short* __restrict__ xT, unsigned short* __restrict__ xqT,
    unsigned short* __restrict__ xkT, unsigned short* __restrict__ xv_bf,
    float* __restrict__ out) {
  __shared__ float shbuf[64 * 133];
  int bz = blockIdx.x, t = threadIdx.x;
  if (bz < 512) {
    // convert W1, W2: 131072 float4s
    int id = bz * 256 + t;
    const float4* s; unsigned short* d; int k;
    if (id < 65536) { s = W1; d = w1_bf; k = id; }
    else            { s = W2; d = w2_bf; k = id - 65536; }
    float4 v = s[k];
    ushort4 o; o.x = f2bf(v.x); o.y = f2bf(v.y); o.z = f2bf(v.z); o.w = f2bf(v.w);
    *(ushort4*)&d[k * 4] = o;
  } else if (bz < 768) {
    // transpose x[b][c][n] -> xT[b][n][c] bf16 (b<4)
    float (*tile)[65] = (float(*)[65])shbuf;
    int zz = bz - 512;
    int b = zz >> 6, c0 = ((zz >> 4) & 3) * 64, n0 = (zz & 15) * 64;
    int tr = t >> 6, tc = t & 63;
#pragma unroll
    for (int r = 0; r < 16; ++r) {
      int c = tr + r * 4;
      tile[c][tc] = x[(long)b * CN + (long)(c0 + c) * NN + n0 + tc];
    }
    __syncthreads();
#pragma unroll
    for (int r = 0; r < 16; ++r) {
      int n = tr + r * 4;
      xT[(long)b * CN + (long)(n0 + n) * CC + c0 + tc] = f2bf(tile[tc][n]);
    }
  } else if (bz < 1792) {
    // grouped q/k projections -> xqT[12], xkT[4]  ([n][c] bf16)
    float (*xs)[68] = (float(*)[68])shbuf;
    float (*Ws)[65] = (float(*)[65])(shbuf + 64 * 68);
    int zz = bz - 768;
    int z = zz >> 6, g = (zz >> 4) & 3, n0 = (zz & 15) * 64;
    const float* src; const float* W; unsigned short* dst;
    if (z < 12) { src = x + (long)(4 + z) * CN; W = Wq; dst = xqT + (long)z * CN; }
    else        { src = x + (long)(z - 12) * CN; W = Wk; dst = xkT + (long)(z - 12) * CN; }
    int tr = t >> 6, tc = t & 63;
#pragma unroll
    for (int r = 0; r < 16; ++r) {
      int i = tr + r * 4;
      xs[i][tc] = src[(long)(g * 64 + i) * NN + n0 + tc];
      Ws[i][tc] = W[(g * 64 + i) * 64 + tc];
    }
    __syncthreads();
    int o = tc, q = tr;
    float acc[16];
#pragma unroll
    for (int k = 0; k < 16; ++k) acc[k] = 0.f;
    for (int i = 0; i < 64; ++i) {
      float w = Ws[o][i];
      const float4* xr4 = (const float4*)&xs[i][q * 16];
#pragma unroll
      for (int k = 0; k < 4; ++k) {
        float4 v = xr4[k];
        acc[4*k+0] += w * v.x; acc[4*k+1] += w * v.y;
        acc[4*k+2] += w * v.z; acc[4*k+3] += w * v.w;
      }
    }
#pragma unroll
    for (int k = 0; k < 16; ++k)
      dst[(long)(n0 + q * 16 + k) * CC + g * 64 + o] = f2bf(acc[k]);
  } else if (bz < 2048) {
    // xv projection: xv_bf[b][o][n] = sum_c Wv[o][c] x[b][c][n] + bv[o]  (b<4)
    float (*xs)[68] = (float(*)[68])shbuf;
    float (*Ws)[65] = (float(*)[65])(shbuf + 64 * 68);
    int zz = bz - 1792;
    int b = zz >> 6, o0 = ((zz >> 4) & 3) * 64, n0 = (zz & 15) * 64;
    int tr = t >> 6, tc = t & 63;
    float acc[16];
#pragma unroll
    for (int k = 0; k < 16; ++k) acc[k] = 0.f;
    for (int cb = 0; cb < 4; ++cb) {
      __syncthreads();
#pragma unroll
      for (int r = 0; r < 16; ++r) {
        int i = tr + r * 4;
        xs[i][tc] = x[(long)b * CN + (long)(cb * 64 + i) * NN + n0 + tc];
        Ws[i][tc] = Wv[(long)(o0 + i) * 256 + cb * 64 + tc];
      }
      __syncthreads();
      for (int i = 0; i < 64; ++i) {
        float w = Ws[tc][i];
        const float4* xr4 = (const float4*)&xs[i][tr * 16];
#pragma unroll
        for (int k = 0; k < 4; ++k) {
          float4 v = xr4[k];
          acc[4*k+0] += w * v.x; acc[4*k+1] += w * v.y;
          acc[4*k+2] += w * v.z; acc[4*k+3] += w * v.w;
        }
      }
    }
    float bvv = bv[o0 + tc];
#pragma unroll
    for (int k = 0; k < 16; ++k)
      xv_bf[((long)b * CC + o0 + tc) * NN + n0 + tr * 16 + k] = f2bf(acc[k] + bvv);
  } else {
    // passthrough copy out[4..15] = x[4..15]: 786432 float4s
    int zz = bz - 2048;    // 0..767
    const float4* src = (const float4*)(x + 4L * CN);
    float4* dst = (float4*)(out + 4L * CN);
#pragma unroll
    for (int k = 0; k < 4; ++k) {
      int idx = zz * 1024 + k * 256 + t;
      dst[idx] = src[idx];
    }
  }
}

// ---------- bf16 MFMA GEMM, 128x128 tile; optional fused column-softmax stats ----------
template<int BIASROW, int BIASCOL, int RELU, int OUTBF, int STATS>
__global__ __launch_bounds__(256) void mgemm(
    const unsigned short* __restrict__ A, const unsigned short* __restrict__ B,
    void* __restrict__ Cout, const float* __restrict__ bias,
    float2* __restrict__ part,
    int lda, int ldb, int ldc, int K,
    long sA, int amod, long sB, int bmod, long sC, float alpha) {
  __shared__ unsigned short As[128 * 32];
  __shared__ unsigned short Bs[128 * 32];
  int z = blockIdx.z;
  A += (long)(z % amod) * sA;
  B += (long)(z % bmod) * sB;
  int t = threadIdx.x, w = t >> 6, l = t & 63;
  int wr = w >> 1, wc = w & 1;
  long i0 = blockIdx.y * 128, j0 = blockIdx.x * 128;
  f32x4 acc[4][4];
#pragma unroll
  for (int a = 0; a < 4; ++a)
#pragma unroll
    for (int b = 0; b < 4; ++b) acc[a][b] = (f32x4){0.f, 0.f, 0.f, 0.f};
  int lr = l & 15, lk = (l >> 4) * 8;
  for (int k0 = 0; k0 < K; k0 += 32) {
#pragma unroll
    for (int it = 0; it < 2; ++it) {
      int chunk = t + it * 256;
      int row = chunk >> 2, kq = chunk & 3;
      gload_lds16(A + (i0 + row) * (long)lda + k0 + kq * 8, &As[chunk * 8]);
      gload_lds16(B + (j0 + row) * (long)ldb + k0 + kq * 8, &Bs[chunk * 8]);
    }
    __syncthreads();
    short8 af[4], bfr[4];
#pragma unroll
    for (int f = 0; f < 4; ++f) af[f]  = *(const short8*)&As[(wr * 64 + f * 16 + lr) * 32 + lk];
#pragma unroll
    for (int f = 0; f < 4; ++f) bfr[f] = *(const short8*)&Bs[(wc * 64 + f * 16 + lr) * 32 + lk];
#pragma unroll
    for (int fm = 0; fm < 4; ++fm)
#pragma unroll
      for (int fn = 0; fn < 4; ++fn)
        acc[fm][fn] = __builtin_amdgcn_mfma_f32_16x16x32_bf16(af[fm], bfr[fn], acc[fm][fn], 0, 0, 0);
    __syncthreads();
  }
  long cz = (long)z * sC;
  int li = (l >> 4) * 4, lj = l & 15;
#pragma unroll
  for (int fm = 0; fm < 4; ++fm)
#pragma unroll
    for (int fn = 0; fn < 4; ++fn) {
      long ib = i0 + wr * 64 + fm * 16 + li;
      long j  = j0 + wc * 64 + fn * 16 + lj;
#pragma unroll
      for (int r = 0; r < 4; ++r) {
        long i = ib + r;
        float v = acc[fm][fn][r] * alpha;
        if (BIASCOL) v += bias[j];
        if (BIASROW) v += bias[i];
        if (RELU)    v = fmaxf(v, 0.f);
        if (OUTBF) ((unsigned short*)Cout)[cz + i * ldc + j] = f2bf(v);
        else       ((float*)Cout)[cz + i * ldc + j] = v;
      }
    }
  if (STATS) {
    int chunk = blockIdx.y * 2 + wr;
#pragma unroll
    for (int fn = 0; fn < 4; ++fn) {
      float mx = -1e30f;
#pragma unroll
      for (int fm = 0; fm < 4; ++fm)
#pragma unroll
        for (int r = 0; r < 4; ++r) mx = fmaxf(mx, acc[fm][fn][r]);
      mx = fmaxf(mx, __shfl_xor(mx, 16));
      mx = fmaxf(mx, __shfl_xor(mx, 32));
      float sm = 0.f;
#pragma unroll
      for (int fm = 0; fm < 4; ++fm)
#pragma unroll
        for (int r = 0; r < 4; ++r) sm += __expf(acc[fm][fn][r] - mx);
      sm += __shfl_xor(sm, 16);
      sm += __shfl_xor(sm, 32);
      if (l < 16) {
        long n = j0 + wc * 64 + fn * 16 + l;
        part[((long)z * 16 + chunk) * NN + n] = make_float2(mx, sm);
      }
    }
  }
}

// ---------- PV GEMM, K-split x4, fused stat-combine + exp; bf16 partials ----------
__global__ __launch_bounds__(256) void pv_gemm(
    const unsigned short* __restrict__ E, const unsigned short* __restrict__ XV,
    const float2* __restrict__ part, unsigned short* __restrict__ xrp) {
  __shared__ unsigned short As[128 * 32];
  __shared__ unsigned short Bs[128 * 32];
  __shared__ float Ms[256];
  __shared__ float Ds[256];
  int z = blockIdx.z;
  int q = z >> 2, s = z & 3;
  const unsigned short* A = E + (long)q * NN * NN + s * 256;
  const unsigned short* B = XV + (long)(q & 3) * CN + s * 256;
  int t = threadIdx.x;
  {
    int n = s * 256 + t;
    float mx = -1e30f;
#pragma unroll
    for (int c = 0; c < 16; ++c) mx = fmaxf(mx, part[((long)q * 16 + c) * NN + n].x);
    float sm = 0.f;
#pragma unroll
    for (int c = 0; c < 16; ++c) {
      float2 p = part[((long)q * 16 + c) * NN + n];
      sm += p.y * __expf(p.x - mx);
    }
    Ms[t] = mx;
    Ds[t] = 1.f / sm;
  }
  int w = t >> 6, l = t & 63;
  int wr = w >> 1, wc = w & 1;
  long i0 = blockIdx.y * 128, j0 = blockIdx.x * 128;
  f32x4 acc[4][4];
#pragma unroll
  for (int a = 0; a < 4; ++a)
#pragma unroll
    for (int b = 0; b < 4; ++b) acc[a][b] = (f32x4){0.f, 0.f, 0.f, 0.f};
  int lr = l & 15, lk = (l >> 4) * 8;
  int ar = t >> 1, ah = (t & 1) * 16;
  __syncthreads();
  for (int k0 = 0; k0 < 256; k0 += 32) {
#pragma unroll
    for (int it = 0; it < 2; ++it) {
      int chunk = t + it * 256;
      int row = chunk >> 2, kq = chunk & 3;
      gload_lds16(B + (j0 + row) * 1024L + k0 + kq * 8, &Bs[chunk * 8]);
    }
    u16x8 e0 = *(const u16x8*)&A[(i0 + ar) * 1024L + k0 + ah];
    u16x8 e1 = *(const u16x8*)&A[(i0 + ar) * 1024L + k0 + ah + 8];
    u16x8 p0, p1;
#pragma unroll
    for (int j = 0; j < 8; ++j) {
      int n = k0 + ah + j;
      p0[j] = f2bf(__expf(bf2f(e0[j]) - Ms[n]) * Ds[n]);
    }
#pragma unroll
    for (int j = 0; j < 8; ++j) {
      int n = k0 + ah + 8 + j;
      p1[j] = f2bf(__expf(bf2f(e1[j]) - Ms[n]) * Ds[n]);
    }
    *(u16x8*)&As[ar * 32 + ah]     = p0;
    *(u16x8*)&As[ar * 32 + ah + 8] = p1;
    __syncthreads();
    short8 af[4], bfr[4];
#pragma unroll
    for (int f = 0; f < 4; ++f) af[f]  = *(const short8*)&As[(wr * 64 + f * 16 + lr) * 32 + lk];
#pragma unroll
    for (int f = 0; f < 4; ++f) bfr[f] = *(const short8*)&Bs[(wc * 64 + f * 16 + lr) * 32 + lk];
#pragma unroll
    for (int fm = 0; fm < 4; ++fm)
#pragma unroll
      for (int fn = 0; fn < 4; ++fn)
        acc[fm][fn] = __builtin_amdgcn_mfma_f32_16x16x32_bf16(af[fm], bfr[fn], acc[fm][fn], 0, 0, 0);
    __syncthreads();
  }
  long cz = (long)(s * 12 + q) << 18;
  int li = (l >> 4) * 4, lj = l & 15;
#pragma unroll
  for (int fm = 0; fm < 4; ++fm)
#pragma unroll
    for (int fn = 0; fn < 4; ++fn) {
      long ib = i0 + wr * 64 + fm * 16 + li;
      long j  = j0 + wc * 64 + fn * 16 + lj;
#pragma unroll
      for (int r = 0; r < 4; ++r)
        xrp[cz + (ib + r) * 256 + j] = f2bf(acc[fm][fn][r] * (1.f / 16.f));
    }
}

// ---------- mix (reshape-mean over 12 bf16 partials) + residual + LN1 ----------
__global__ __launch_bounds__(256) void mix_ln1(
    const unsigned short* __restrict__ xT, const unsigned short* __restrict__ xrp,
    const float* __restrict__ g, const float* __restrict__ bb,
    unsigned short* __restrict__ h_bf) {
  __shared__ float r1[4], r2[4];
  int bn = blockIdx.x;
  int i = bn >> 10, n = bn & 1023;
  int c = threadIdx.x;
  long no = (long)n * CC + c;
  float a = 0.f;
#pragma unroll
  for (int j = 0; j < 3; ++j)
#pragma unroll
    for (int s = 0; s < 4; ++s)
      a += bf2f(xrp[((long)(s * 12 + 3 * i + j) << 18) + no]);
  float v = bf2f(xT[(long)i * CN + no]) + a * (1.f / 3.f);
  float sS = v, s2 = v * v;
#pragma unroll
  for (int m = 32; m; m >>= 1) { sS += __shfl_xor(sS, m); s2 += __shfl_xor(s2, m); }
  if ((c & 63) == 0) { r1[c >> 6] = sS; r2[c >> 6] = s2; }
  __syncthreads();
  float mu = (r1[0] + r1[1] + r1[2] + r1[3]) * (1.f / 256.f);
  float var = (r2[0] + r2[1] + r2[2] + r2[3]) * (1.f / 256.f) - mu * mu;
  float o = (v - mu) * rsqrtf(var + 1e-6f) * g[c] + bb[c];
  h_bf[(long)bn * CC + c] = f2bf(o);
}

// ---------- combine MLP2 bf16 partials + bias + residual + LN2 + relu + transpose ----------
__global__ __launch_bounds__(256) void ln2t(
    const unsigned short* __restrict__ pm, const unsigned short* __restrict__ h_bf,
    const float* __restrict__ b2, const float* __restrict__ g,
    const float* __restrict__ bb, float* __restrict__ out) {
  __shared__ float tile[16][261];
  __shared__ float smu[16], srs[16];
  int i = blockIdx.y, n0 = blockIdx.x * 16;
  int t = threadIdx.x;
  float bc = b2[t];
#pragma unroll
  for (int r = 0; r < 16; ++r) {
    long row = (long)i * NN + n0 + r;
    float v = bc + bf2f(h_bf[row * CC + t]);
#pragma unroll
    for (int s = 0; s < 4; ++s) v += bf2f(pm[((long)s << 20) + row * CC + t]);
    tile[r][t] = v;
  }
  __syncthreads();
  int w = t >> 6, l = t & 63;
#pragma unroll
  for (int rr = 0; rr < 4; ++rr) {
    int r = w * 4 + rr;
    float s = 0.f, s2 = 0.f;
#pragma unroll
    for (int k = 0; k < 4; ++k) { float v = tile[r][l + 64 * k]; s += v; s2 += v * v; }
#pragma unroll
    for (int m = 32; m; m >>= 1) { s += __shfl_xor(s, m); s2 += __shfl_xor(s2, m); }
    if (l == 0) {
      float mu = s * (1.f / 256.f);
      float var = s2 * (1.f / 256.f) - mu * mu;
      smu[r] = mu; srs[r] = rsqrtf(var + 1e-6f);
    }
  }
  __syncthreads();
#pragma unroll
  for (int k = 0; k < 16; ++k) {
    int nn = t & 15, c = (t >> 4) + 16 * k;
    float v = (tile[nn][c] - smu[nn]) * srs[nn] * g[c] + bb[c];
    out[((long)i * CC + c) * NN + n0 + nn] = fmaxf(v, 0.f);
  }
}

extern "C" void kernel_launch(void* const* d_in, const int* in_sizes, int n_in,
                              void* d_out, int out_size, void* d_ws, size_t ws_size,
                              hipStream_t stream) {
  const float* x   = (const float*)d_in[0];
  const float* Wq  = (const float*)d_in[1];
  const float* Wk  = (const float*)d_in[2];
  const float* Wv  = (const float*)d_in[3];
  const float* bv  = (const float*)d_in[4];
  const float* g1  = (const float*)d_in[5];
  const float* b1v = (const float*)d_in[6];
  const float* W1  = (const float*)d_in[7];
  const float* b1m = (const float*)d_in[8];
  const float* W2  = (const float*)d_in[9];
  const float* b2m = (const float*)d_in[10];
  const float* g2  = (const float*)d_in[11];
  const float* b2v = (const float*)d_in[12];
  float* out = (float*)d_out;

  char* base = (char*)d_ws;
  // [0,24MB): E_bf; reused after pv: h_bf [0,2), hid_bf [2,10)
  unsigned short* E_bf   = (unsigned short*)base;
  unsigned short* h_bf   = (unsigned short*)base;
  unsigned short* hid_bf = (unsigned short*)(base + (2u << 20));
  size_t off = 24u << 20;
  unsigned short* xrp    = (unsigned short*)(base + off); off += 25165824;  // 24MB
  unsigned short* p_mlp  = (unsigned short*)(base + off); off += 8388608;   // 8MB
  unsigned short* w1_bf  = (unsigned short*)(base + off); off += 524288;
  unsigned short* w2_bf  = (unsigned short*)(base + off); off += 524288;
  unsigned short* xt_bf  = (unsigned short*)(base + off); off += 2097152;
  unsigned short* xqt_bf = (unsigned short*)(base + off); off += 6291456;
  unsigned short* xkt_bf = (unsigned short*)(base + off); off += 2097152;
  unsigned short* xv_bf  = (unsigned short*)(base + off); off += 2097152;
  float2* part           = (float2*)(base + off);         off += 1572864;

  // 1. prep: W1/W2 convert (512) + x-transpose (256) + q/k proj (1024)
  //          + xv proj (256) + passthrough copy (768)
  prep_kernel<<<2816, 256, 0, stream>>>(x, Wq, Wk, Wv, bv,
      (const float4*)W1, (const float4*)W2, w1_bf, w2_bf,
      xt_bf, xqt_bf, xkt_bf, xv_bf, out);
  // 2. E'[q][m][n] = sum_c xk[c][m] xq[c][n]  (bf16) + fused per-column stats
  mgemm<0,0,0,1,1><<<dim3(8, 8, 12), 256, 0, stream>>>(
      xkt_bf, xqt_bf, E_bf, nullptr, part,
      256, 256, 1024, 256, (long)CN, 4, (long)CN, 12, (long)NN * NN, 1.f);
  // 3. PV (K-split x4) with fused stat-combine + exp -> xrp bf16
  pv_gemm<<<dim3(2, 8, 48), 256, 0, stream>>>(E_bf, xv_bf, part, xrp);
  // 4. mix + LN1 -> h_bf
  mix_ln1<<<4096, 256, 0, stream>>>(xt_bf, xrp, g1, b1v, h_bf);
  // 5. hid = relu(h @ W1^T + b1) -> bf16
  mgemm<0,1,1,1,0><<<dim3(8, 32, 1), 256, 0, stream>>>(
      h_bf, w1_bf, hid_bf, b1m, nullptr,
      256, 256, 1024, 256, 0L, 1, 0L, 1, 0L, 1.f);
  // 6. MLP2 partials (K-split x4) -> bf16
  mgemm<0,0,0,1,0><<<dim3(2, 32, 4), 256, 0, stream>>>(
      hid_bf, w2_bf, p_mlp, nullptr, nullptr,
      1024, 1024, 256, 256, 256L, 4, 256L, 4, 1048576L, 1.f);
  // 7. combine + bias + residual + LN2 + relu + transpose -> out[0..3]
  ln2t<<<dim3(64, 4), 256, 0, stream>>>(p_mlp, h_bf, b2m, g2, b2v, out);
}

// Round 6
// 178.191 us; speedup vs baseline: 1.1258x; 1.1258x over previous
//
#include <hip/hip_runtime.h>

#define CC 256
#define NN 1024
#define CN (CC*NN)

typedef __attribute__((ext_vector_type(8))) short short8;
typedef __attribute__((ext_vector_type(8))) unsigned short u16x8;
typedef __attribute__((ext_vector_type(4))) float f32x4;

__device__ __forceinline__ unsigned short f2bf(float x) {
  unsigned u = __float_as_uint(x);
  u = u + 0x7fffu + ((u >> 16) & 1u);
  return (unsigned short)(u >> 16);
}
__device__ __forceinline__ float bf2f(unsigned short b) {
  return __uint_as_float(((unsigned)b) << 16);
}
__device__ __forceinline__ void gload_lds16(const unsigned short* g, unsigned short* l) {
  __builtin_amdgcn_global_load_lds(
      (const __attribute__((address_space(1))) unsigned short*)g,
      (__attribute__((address_space(3))) unsigned short*)l, 16, 0, 0);
}

// ---------- prep: copy-out FIRST, then W convert, x-transpose, q/k proj ----------
__global__ __launch_bounds__(256) void prep_kernel(
    const float* __restrict__ x, const float* __restrict__ Wq,
    const float* __restrict__ Wk, const float4* __restrict__ Wv,
    const float4* __restrict__ W1, const float4* __restrict__ W2,
    unsigned short* __restrict__ wv_bf,
    unsigned short* __restrict__ w1_bf, unsigned short* __restrict__ w2_bf,
    unsigned short* __restrict__ xT, unsigned short* __restrict__ xqT,
    unsigned short* __restrict__ xkT, float* __restrict__ out) {
  __shared__ float shbuf[6464];   // 25.9 KB -> 6 blocks/CU
  int bz = blockIdx.x, t = threadIdx.x;
  if (bz < 768) {
    // passthrough copy out[4..15] = x[4..15]: 786432 float4s, streams first
    const float4* src = (const float4*)(x + 4L * CN);
    float4* dst = (float4*)(out + 4L * CN);
#pragma unroll
    for (int k = 0; k < 4; ++k) {
      int idx = bz * 1024 + k * 256 + t;
      dst[idx] = src[idx];
    }
  } else if (bz < 1344) {
    // convert Wv (16384) + W1 (65536) + W2 (65536) = 147456 float4s
    int id = (bz - 768) * 256 + t;
    const float4* s; unsigned short* d; int k;
    if (id < 16384)      { s = Wv; d = wv_bf; k = id; }
    else if (id < 81920) { s = W1; d = w1_bf; k = id - 16384; }
    else                 { s = W2; d = w2_bf; k = id - 81920; }
    float4 v = s[k];
    ushort4 o; o.x = f2bf(v.x); o.y = f2bf(v.y); o.z = f2bf(v.z); o.w = f2bf(v.w);
    *(ushort4*)&d[k * 4] = o;
  } else if (bz < 1600) {
    // transpose x[b][c][n] -> xT[b][n][c] bf16 (b<4)
    float (*tile)[65] = (float(*)[65])shbuf;
    int zz = bz - 1344;
    int b = zz >> 6, c0 = ((zz >> 4) & 3) * 64, n0 = (zz & 15) * 64;
    int tr = t >> 6, tc = t & 63;
#pragma unroll
    for (int r = 0; r < 16; ++r) {
      int c = tr + r * 4;
      tile[c][tc] = x[(long)b * CN + (long)(c0 + c) * NN + n0 + tc];
    }
    __syncthreads();
#pragma unroll
    for (int r = 0; r < 16; ++r) {
      int n = tr + r * 4;
      xT[(long)b * CN + (long)(n0 + n) * CC + c0 + tc] = f2bf(tile[tc][n]);
    }
  } else {
    // grouped q/k projections, 32-wide n-chunks -> 2048 blocks
    float (*Ws)[65] = (float(*)[65])shbuf;               // 64x65
    float (*xs)[36] = (float(*)[36])(shbuf + 64 * 65);   // 64x36
    int zz = bz - 1600;                 // 0..2047
    int z = zz >> 7, g = (zz >> 5) & 3, n0 = (zz & 31) * 32;
    const float* src; const float* W; unsigned short* dst;
    if (z < 12) { src = x + (long)(4 + z) * CN; W = Wq; dst = xqT + (long)z * CN; }
    else        { src = x + (long)(z - 12) * CN; W = Wk; dst = xkT + (long)(z - 12) * CN; }
    int tr = t >> 6, tc = t & 63;
#pragma unroll
    for (int r = 0; r < 16; ++r) {
      int i = tr + r * 4;
      Ws[i][tc] = W[(g * 64 + i) * 64 + tc];
    }
#pragma unroll
    for (int r = 0; r < 8; ++r) {
      int i = r * 8 + (t >> 5);
      xs[i][t & 31] = src[(long)(g * 64 + i) * NN + n0 + (t & 31)];
    }
    __syncthreads();
    int o = tc, qd = tr;   // qd uniform per wave
    float acc[8];
#pragma unroll
    for (int k = 0; k < 8; ++k) acc[k] = 0.f;
    for (int i = 0; i < 64; ++i) {
      float w = Ws[o][i];
      const float4* xr4 = (const float4*)&xs[i][qd * 8];
      float4 a0 = xr4[0], a1 = xr4[1];
      acc[0] += w * a0.x; acc[1] += w * a0.y; acc[2] += w * a0.z; acc[3] += w * a0.w;
      acc[4] += w * a1.x; acc[5] += w * a1.y; acc[6] += w * a1.z; acc[7] += w * a1.w;
    }
#pragma unroll
    for (int k = 0; k < 8; ++k)
      dst[(long)(n0 + qd * 8 + k) * CC + g * 64 + o] = f2bf(acc[k]);
  }
}

// ---------- attention GEMM: z<64 -> xv projection; z>=64 -> energy + stats ----------
__global__ __launch_bounds__(256) void attn_gemm(
    const unsigned short* __restrict__ xkt, const unsigned short* __restrict__ xqt,
    const unsigned short* __restrict__ wv, const unsigned short* __restrict__ xt,
    const float* __restrict__ bv, unsigned short* __restrict__ E,
    unsigned short* __restrict__ xv, float2* __restrict__ part) {
  __shared__ unsigned short As[128 * 32];
  __shared__ unsigned short Bs[128 * 32];
  int z = blockIdx.x;
  const unsigned short *A, *B;
  unsigned short* Co;
  long i0, j0;
  int q = 0;
  bool isXV = z < 64;
  if (isXV) {
    int b = z >> 4, r = z & 15;
    i0 = (r >> 3) * 128; j0 = (r & 7) * 128;
    A = wv; B = xt + (long)b * CN; Co = xv + (long)b * CN;
  } else {
    int ze = z - 64;
    q = ze >> 6; int r = ze & 63;
    i0 = (r >> 3) * 128; j0 = (r & 7) * 128;
    A = xkt + (long)(q & 3) * CN; B = xqt + (long)q * CN;
    Co = E + (long)q * NN * NN;
  }
  int t = threadIdx.x, w = t >> 6, l = t & 63;
  int wr = w >> 1, wc = w & 1;
  f32x4 acc[4][4];
#pragma unroll
  for (int a = 0; a < 4; ++a)
#pragma unroll
    for (int b = 0; b < 4; ++b) acc[a][b] = (f32x4){0.f, 0.f, 0.f, 0.f};
  int lr = l & 15, lk = (l >> 4) * 8;
  for (int k0 = 0; k0 < 256; k0 += 32) {
#pragma unroll
    for (int it = 0; it < 2; ++it) {
      int chunk = t + it * 256;
      int row = chunk >> 2, kq = chunk & 3;
      gload_lds16(A + (i0 + row) * 256L + k0 + kq * 8, &As[chunk * 8]);
      gload_lds16(B + (j0 + row) * 256L + k0 + kq * 8, &Bs[chunk * 8]);
    }
    __syncthreads();
    short8 af[4], bfr[4];
#pragma unroll
    for (int f = 0; f < 4; ++f) af[f]  = *(const short8*)&As[(wr * 64 + f * 16 + lr) * 32 + lk];
#pragma unroll
    for (int f = 0; f < 4; ++f) bfr[f] = *(const short8*)&Bs[(wc * 64 + f * 16 + lr) * 32 + lk];
#pragma unroll
    for (int fm = 0; fm < 4; ++fm)
#pragma unroll
      for (int fn = 0; fn < 4; ++fn)
        acc[fm][fn] = __builtin_amdgcn_mfma_f32_16x16x32_bf16(af[fm], bfr[fn], acc[fm][fn], 0, 0, 0);
    __syncthreads();
  }
  int li = (l >> 4) * 4, lj = l & 15;
#pragma unroll
  for (int fm = 0; fm < 4; ++fm)
#pragma unroll
    for (int fn = 0; fn < 4; ++fn) {
      long ib = i0 + wr * 64 + fm * 16 + li;
      long j  = j0 + wc * 64 + fn * 16 + lj;
#pragma unroll
      for (int r = 0; r < 4; ++r) {
        float v = acc[fm][fn][r];
        if (isXV) v += bv[ib + r];
        Co[(ib + r) * 1024 + j] = f2bf(v);
      }
    }
  if (!isXV) {
    int chunk = (int)(i0 >> 6) + wr;
#pragma unroll
    for (int fn = 0; fn < 4; ++fn) {
      float mx = -1e30f;
#pragma unroll
      for (int fm = 0; fm < 4; ++fm)
#pragma unroll
        for (int r = 0; r < 4; ++r) mx = fmaxf(mx, acc[fm][fn][r]);
      mx = fmaxf(mx, __shfl_xor(mx, 16));
      mx = fmaxf(mx, __shfl_xor(mx, 32));
      float sm = 0.f;
#pragma unroll
      for (int fm = 0; fm < 4; ++fm)
#pragma unroll
        for (int r = 0; r < 4; ++r) sm += __expf(acc[fm][fn][r] - mx);
      sm += __shfl_xor(sm, 16);
      sm += __shfl_xor(sm, 32);
      if (l < 16) {
        long n = j0 + wc * 64 + fn * 16 + l;
        part[((long)q * 16 + chunk) * NN + n] = make_float2(mx, sm);
      }
    }
  }
}

// ---------- bf16 MFMA GEMM (MLP shapes) ----------
template<int BIASCOL, int RELU>
__global__ __launch_bounds__(256) void mgemm(
    const unsigned short* __restrict__ A, const unsigned short* __restrict__ B,
    unsigned short* __restrict__ Cout, const float* __restrict__ bias,
    int lda, int ldb, int ldc, int K,
    long sA, int amod, long sB, int bmod, long sC) {
  __shared__ unsigned short As[128 * 32];
  __shared__ unsigned short Bs[128 * 32];
  int z = blockIdx.z;
  A += (long)(z % amod) * sA;
  B += (long)(z % bmod) * sB;
  int t = threadIdx.x, w = t >> 6, l = t & 63;
  int wr = w >> 1, wc = w & 1;
  long i0 = blockIdx.y * 128, j0 = blockIdx.x * 128;
  f32x4 acc[4][4];
#pragma unroll
  for (int a = 0; a < 4; ++a)
#pragma unroll
    for (int b = 0; b < 4; ++b) acc[a][b] = (f32x4){0.f, 0.f, 0.f, 0.f};
  int lr = l & 15, lk = (l >> 4) * 8;
  for (int k0 = 0; k0 < K; k0 += 32) {
#pragma unroll
    for (int it = 0; it < 2; ++it) {
      int chunk = t + it * 256;
      int row = chunk >> 2, kq = chunk & 3;
      gload_lds16(A + (i0 + row) * (long)lda + k0 + kq * 8, &As[chunk * 8]);
      gload_lds16(B + (j0 + row) * (long)ldb + k0 + kq * 8, &Bs[chunk * 8]);
    }
    __syncthreads();
    short8 af[4], bfr[4];
#pragma unroll
    for (int f = 0; f < 4; ++f) af[f]  = *(const short8*)&As[(wr * 64 + f * 16 + lr) * 32 + lk];
#pragma unroll
    for (int f = 0; f < 4; ++f) bfr[f] = *(const short8*)&Bs[(wc * 64 + f * 16 + lr) * 32 + lk];
#pragma unroll
    for (int fm = 0; fm < 4; ++fm)
#pragma unroll
      for (int fn = 0; fn < 4; ++fn)
        acc[fm][fn] = __builtin_amdgcn_mfma_f32_16x16x32_bf16(af[fm], bfr[fn], acc[fm][fn], 0, 0, 0);
    __syncthreads();
  }
  long cz = (long)z * sC;
  int li = (l >> 4) * 4, lj = l & 15;
#pragma unroll
  for (int fm = 0; fm < 4; ++fm)
#pragma unroll
    for (int fn = 0; fn < 4; ++fn) {
      long ib = i0 + wr * 64 + fm * 16 + li;
      long j  = j0 + wc * 64 + fn * 16 + lj;
#pragma unroll
      for (int r = 0; r < 4; ++r) {
        float v = acc[fm][fn][r];
        if (BIASCOL) v += bias[j];
        if (RELU)    v = fmaxf(v, 0.f);
        Cout[cz + (ib + r) * ldc + j] = f2bf(v);
      }
    }
}

// ---------- PV GEMM, K-split x4, fused stat-combine + exp; bf16 partials ----------
__global__ __launch_bounds__(256) void pv_gemm(
    const unsigned short* __restrict__ E, const unsigned short* __restrict__ XV,
    const float2* __restrict__ part, unsigned short* __restrict__ xrp) {
  __shared__ unsigned short As[128 * 32];
  __shared__ unsigned short Bs[128 * 32];
  __shared__ float Ms[256];
  __shared__ float Ds[256];
  int z = blockIdx.z;
  int q = z >> 2, s = z & 3;
  const unsigned short* A = E + (long)q * NN * NN + s * 256;
  const unsigned short* B = XV + (long)(q & 3) * CN + s * 256;
  int t = threadIdx.x;
  {
    int n = s * 256 + t;
    float mx = -1e30f;
#pragma unroll
    for (int c = 0; c < 16; ++c) mx = fmaxf(mx, part[((long)q * 16 + c) * NN + n].x);
    float sm = 0.f;
#pragma unroll
    for (int c = 0; c < 16; ++c) {
      float2 p = part[((long)q * 16 + c) * NN + n];
      sm += p.y * __expf(p.x - mx);
    }
    Ms[t] = mx;
    Ds[t] = 1.f / sm;
  }
  int w = t >> 6, l = t & 63;
  int wr = w >> 1, wc = w & 1;
  long i0 = blockIdx.y * 128, j0 = blockIdx.x * 128;
  f32x4 acc[4][4];
#pragma unroll
  for (int a = 0; a < 4; ++a)
#pragma unroll
    for (int b = 0; b < 4; ++b) acc[a][b] = (f32x4){0.f, 0.f, 0.f, 0.f};
  int lr = l & 15, lk = (l >> 4) * 8;
  int ar = t >> 1, ah = (t & 1) * 16;
  __syncthreads();
  for (int k0 = 0; k0 < 256; k0 += 32) {
#pragma unroll
    for (int it = 0; it < 2; ++it) {
      int chunk = t + it * 256;
      int row = chunk >> 2, kq = chunk & 3;
      gload_lds16(B + (j0 + row) * 1024L + k0 + kq * 8, &Bs[chunk * 8]);
    }
    u16x8 e0 = *(const u16x8*)&A[(i0 + ar) * 1024L + k0 + ah];
    u16x8 e1 = *(const u16x8*)&A[(i0 + ar) * 1024L + k0 + ah + 8];
    u16x8 p0, p1;
#pragma unroll
    for (int j = 0; j < 8; ++j) {
      int n = k0 + ah + j;
      p0[j] = f2bf(__expf(bf2f(e0[j]) - Ms[n]) * Ds[n]);
    }
#pragma unroll
    for (int j = 0; j < 8; ++j) {
      int n = k0 + ah + 8 + j;
      p1[j] = f2bf(__expf(bf2f(e1[j]) - Ms[n]) * Ds[n]);
    }
    *(u16x8*)&As[ar * 32 + ah]     = p0;
    *(u16x8*)&As[ar * 32 + ah + 8] = p1;
    __syncthreads();
    short8 af[4], bfr[4];
#pragma unroll
    for (int f = 0; f < 4; ++f) af[f]  = *(const short8*)&As[(wr * 64 + f * 16 + lr) * 32 + lk];
#pragma unroll
    for (int f = 0; f < 4; ++f) bfr[f] = *(const short8*)&Bs[(wc * 64 + f * 16 + lr) * 32 + lk];
#pragma unroll
    for (int fm = 0; fm < 4; ++fm)
#pragma unroll
      for (int fn = 0; fn < 4; ++fn)
        acc[fm][fn] = __builtin_amdgcn_mfma_f32_16x16x32_bf16(af[fm], bfr[fn], acc[fm][fn], 0, 0, 0);
    __syncthreads();
  }
  long cz = (long)(s * 12 + q) << 18;
  int li = (l >> 4) * 4, lj = l & 15;
#pragma unroll
  for (int fm = 0; fm < 4; ++fm)
#pragma unroll
    for (int fn = 0; fn < 4; ++fn) {
      long ib = i0 + wr * 64 + fm * 16 + li;
      long j  = j0 + wc * 64 + fn * 16 + lj;
#pragma unroll
      for (int r = 0; r < 4; ++r)
        xrp[cz + (ib + r) * 256 + j] = f2bf(acc[fm][fn][r] * (1.f / 16.f));
    }
}

// ---------- mix (reshape-mean over 12 bf16 partials) + residual + LN1 ----------
__global__ __launch_bounds__(256) void mix_ln1(
    const unsigned short* __restrict__ xT, const unsigned short* __restrict__ xrp,
    const float* __restrict__ g, const float* __restrict__ bb,
    unsigned short* __restrict__ h_bf) {
  __shared__ float r1[4], r2[4];
  int bn = blockIdx.x;
  int i = bn >> 10, n = bn & 1023;
  int c = threadIdx.x;
  long no = (long)n * CC + c;
  float a = 0.f;
#pragma unroll
  for (int j = 0; j < 3; ++j)
#pragma unroll
    for (int s = 0; s < 4; ++s)
      a += bf2f(xrp[((long)(s * 12 + 3 * i + j) << 18) + no]);
  float v = bf2f(xT[(long)i * CN + no]) + a * (1.f / 3.f);
  float sS = v, s2 = v * v;
#pragma unroll
  for (int m = 32; m; m >>= 1) { sS += __shfl_xor(sS, m); s2 += __shfl_xor(s2, m); }
  if ((c & 63) == 0) { r1[c >> 6] = sS; r2[c >> 6] = s2; }
  __syncthreads();
  float mu = (r1[0] + r1[1] + r1[2] + r1[3]) * (1.f / 256.f);
  float var = (r2[0] + r2[1] + r2[2] + r2[3]) * (1.f / 256.f) - mu * mu;
  float o = (v - mu) * rsqrtf(var + 1e-6f) * g[c] + bb[c];
  h_bf[(long)bn * CC + c] = f2bf(o);
}

// ---------- combine MLP2 bf16 partials + bias + residual + LN2 + relu + transpose ----------
__global__ __launch_bounds__(256) void ln2t(
    const unsigned short* __restrict__ pm, const unsigned short* __restrict__ h_bf,
    const float* __restrict__ b2, const float* __restrict__ g,
    const float* __restrict__ bb, float* __restrict__ out) {
  __shared__ float tile[16][261];
  __shared__ float smu[16], srs[16];
  int i = blockIdx.y, n0 = blockIdx.x * 16;
  int t = threadIdx.x;
  float bc = b2[t];
#pragma unroll
  for (int r = 0; r < 16; ++r) {
    long row = (long)i * NN + n0 + r;
    float v = bc + bf2f(h_bf[row * CC + t]);
#pragma unroll
    for (int s = 0; s < 4; ++s) v += bf2f(pm[((long)s << 20) + row * CC + t]);
    tile[r][t] = v;
  }
  __syncthreads();
  int w = t >> 6, l = t & 63;
#pragma unroll
  for (int rr = 0; rr < 4; ++rr) {
    int r = w * 4 + rr;
    float s = 0.f, s2 = 0.f;
#pragma unroll
    for (int k = 0; k < 4; ++k) { float v = tile[r][l + 64 * k]; s += v; s2 += v * v; }
#pragma unroll
    for (int m = 32; m; m >>= 1) { s += __shfl_xor(s, m); s2 += __shfl_xor(s2, m); }
    if (l == 0) {
      float mu = s * (1.f / 256.f);
      float var = s2 * (1.f / 256.f) - mu * mu;
      smu[r] = mu; srs[r] = rsqrtf(var + 1e-6f);
    }
  }
  __syncthreads();
#pragma unroll
  for (int k = 0; k < 16; ++k) {
    int nn = t & 15, c = (t >> 4) + 16 * k;
    float v = (tile[nn][c] - smu[nn]) * srs[nn] * g[c] + bb[c];
    out[((long)i * CC + c) * NN + n0 + nn] = fmaxf(v, 0.f);
  }
}

extern "C" void kernel_launch(void* const* d_in, const int* in_sizes, int n_in,
                              void* d_out, int out_size, void* d_ws, size_t ws_size,
                              hipStream_t stream) {
  const float* x   = (const float*)d_in[0];
  const float* Wq  = (const float*)d_in[1];
  const float* Wk  = (const float*)d_in[2];
  const float* Wv  = (const float*)d_in[3];
  const float* bv  = (const float*)d_in[4];
  const float* g1  = (const float*)d_in[5];
  const float* b1v = (const float*)d_in[6];
  const float* W1  = (const float*)d_in[7];
  const float* b1m = (const float*)d_in[8];
  const float* W2  = (const float*)d_in[9];
  const float* b2m = (const float*)d_in[10];
  const float* g2  = (const float*)d_in[11];
  const float* b2v = (const float*)d_in[12];
  float* out = (float*)d_out;

  char* base = (char*)d_ws;
  // [0,24MB): E_bf; reused after pv: h_bf [0,2), hid_bf [2,10)
  unsigned short* E_bf   = (unsigned short*)base;
  unsigned short* h_bf   = (unsigned short*)base;
  unsigned short* hid_bf = (unsigned short*)(base + (2u << 20));
  size_t off = 24u << 20;
  unsigned short* xrp    = (unsigned short*)(base + off); off += 25165824;  // 24MB
  unsigned short* p_mlp  = (unsigned short*)(base + off); off += 8388608;   // 8MB
  unsigned short* wv_bf  = (unsigned short*)(base + off); off += 131072;
  unsigned short* w1_bf  = (unsigned short*)(base + off); off += 524288;
  unsigned short* w2_bf  = (unsigned short*)(base + off); off += 524288;
  unsigned short* xt_bf  = (unsigned short*)(base + off); off += 2097152;
  unsigned short* xqt_bf = (unsigned short*)(base + off); off += 6291456;
  unsigned short* xkt_bf = (unsigned short*)(base + off); off += 2097152;
  unsigned short* xv_bf  = (unsigned short*)(base + off); off += 2097152;
  float2* part           = (float2*)(base + off);         off += 1572864;

  // 1. prep: copy (768) + convert (576) + x-transpose (256) + q/k proj (2048)
  prep_kernel<<<3648, 256, 0, stream>>>(x, Wq, Wk, (const float4*)Wv,
      (const float4*)W1, (const float4*)W2, wv_bf, w1_bf, w2_bf,
      xt_bf, xqt_bf, xkt_bf, out);
  // 2. attention GEMMs: xv (64 blocks) + energy/stats (768 blocks)
  attn_gemm<<<832, 256, 0, stream>>>(xkt_bf, xqt_bf, wv_bf, xt_bf,
      bv, E_bf, xv_bf, part);
  // 3. PV (K-split x4) with fused stat-combine + exp -> xrp bf16
  pv_gemm<<<dim3(2, 8, 48), 256, 0, stream>>>(E_bf, xv_bf, part, xrp);
  // 4. mix + LN1 -> h_bf
  mix_ln1<<<4096, 256, 0, stream>>>(xt_bf, xrp, g1, b1v, h_bf);
  // 5. hid = relu(h @ W1^T + b1) -> bf16
  mgemm<1,1><<<dim3(8, 32, 1), 256, 0, stream>>>(
      h_bf, w1_bf, hid_bf, b1m,
      256, 256, 1024, 256, 0L, 1, 0L, 1, 0L);
  // 6. MLP2 partials (K-split x4) -> bf16
  mgemm<0,0><<<dim3(2, 32, 4), 256, 0, stream>>>(
      hid_bf, w2_bf, p_mlp, nullptr,
      1024, 1024, 256, 256, 256L, 4, 256L, 4, 1048576L);
  // 7. combine + bias + residual + LN2 + relu + transpose -> out[0..3]
  ln2t<<<dim3(64, 4), 256, 0, stream>>>(p_mlp, h_bf, b2m, g2, b2v, out);
}

// Round 7
// 175.154 us; speedup vs baseline: 1.1454x; 1.0173x over previous
//
#include <hip/hip_runtime.h>

#define CC 256
#define NN 1024
#define CN (CC*NN)

typedef __attribute__((ext_vector_type(8))) short short8;
typedef __attribute__((ext_vector_type(8))) unsigned short u16x8;
typedef __attribute__((ext_vector_type(4))) float f32x4;

__device__ __forceinline__ unsigned short f2bf(float x) {
  unsigned u = __float_as_uint(x);
  u = u + 0x7fffu + ((u >> 16) & 1u);
  return (unsigned short)(u >> 16);
}
__device__ __forceinline__ float bf2f(unsigned short b) {
  return __uint_as_float(((unsigned)b) << 16);
}
__device__ __forceinline__ void gload_lds16(const unsigned short* g, unsigned short* l) {
  __builtin_amdgcn_global_load_lds(
      (const __attribute__((address_space(1))) unsigned short*)g,
      (__attribute__((address_space(3))) unsigned short*)l, 16, 0, 0);
}

// ---------- prep: q/k proj (writes passthrough out too), x-transpose, W convert ----------
__global__ __launch_bounds__(256) void prep_kernel(
    const float* __restrict__ x, const float* __restrict__ Wq,
    const float* __restrict__ Wk, const float4* __restrict__ Wv,
    const float4* __restrict__ W1, const float4* __restrict__ W2,
    unsigned short* __restrict__ wv_bf,
    unsigned short* __restrict__ w1_bf, unsigned short* __restrict__ w2_bf,
    unsigned short* __restrict__ xT, unsigned short* __restrict__ xqT,
    unsigned short* __restrict__ xkT, float* __restrict__ out) {
  __shared__ float shbuf[6464];   // 25.9 KB -> 6 blocks/CU
  int bz = blockIdx.x, t = threadIdx.x;
  if (bz < 2048) {
    // grouped q/k projections, 32-wide n-chunks; z<12 also writes passthrough out
    float (*Ws)[65] = (float(*)[65])shbuf;               // 64x65
    float (*xs)[36] = (float(*)[36])(shbuf + 64 * 65);   // 64x36
    int zz = bz;                        // 0..2047
    int z = zz >> 7, g = (zz >> 5) & 3, n0 = (zz & 31) * 32;
    const float* src; const float* W; unsigned short* dst;
    float* po = nullptr;
    if (z < 12) {
      src = x + (long)(4 + z) * CN; W = Wq; dst = xqT + (long)z * CN;
      po = out + (long)(4 + z) * CN;
    } else {
      src = x + (long)(z - 12) * CN; W = Wk; dst = xkT + (long)(z - 12) * CN;
    }
    int tr = t >> 6, tc = t & 63;
#pragma unroll
    for (int r = 0; r < 16; ++r) {
      int i = tr + r * 4;
      Ws[i][tc] = W[(g * 64 + i) * 64 + tc];
    }
#pragma unroll
    for (int r = 0; r < 8; ++r) {
      int i = r * 8 + (t >> 5);
      int col = t & 31;
      float v = src[(long)(g * 64 + i) * NN + n0 + col];
      xs[i][col] = v;
      if (po) po[(long)(g * 64 + i) * NN + n0 + col] = v;
    }
    __syncthreads();
    int o = tc, qd = tr;   // qd uniform per wave
    float acc[8];
#pragma unroll
    for (int k = 0; k < 8; ++k) acc[k] = 0.f;
    for (int i = 0; i < 64; ++i) {
      float w = Ws[o][i];
      const float4* xr4 = (const float4*)&xs[i][qd * 8];
      float4 a0 = xr4[0], a1 = xr4[1];
      acc[0] += w * a0.x; acc[1] += w * a0.y; acc[2] += w * a0.z; acc[3] += w * a0.w;
      acc[4] += w * a1.x; acc[5] += w * a1.y; acc[6] += w * a1.z; acc[7] += w * a1.w;
    }
#pragma unroll
    for (int k = 0; k < 8; ++k)
      dst[(long)(n0 + qd * 8 + k) * CC + g * 64 + o] = f2bf(acc[k]);
  } else if (bz < 2304) {
    // transpose x[b][c][n] -> xT[b][n][c] bf16 (b<4)
    float (*tile)[65] = (float(*)[65])shbuf;
    int zz = bz - 2048;
    int b = zz >> 6, c0 = ((zz >> 4) & 3) * 64, n0 = (zz & 15) * 64;
    int tr = t >> 6, tc = t & 63;
#pragma unroll
    for (int r = 0; r < 16; ++r) {
      int c = tr + r * 4;
      tile[c][tc] = x[(long)b * CN + (long)(c0 + c) * NN + n0 + tc];
    }
    __syncthreads();
#pragma unroll
    for (int r = 0; r < 16; ++r) {
      int n = tr + r * 4;
      xT[(long)b * CN + (long)(n0 + n) * CC + c0 + tc] = f2bf(tile[tc][n]);
    }
  } else {
    // convert Wv (16384) + W1 (65536) + W2 (65536) = 147456 float4s
    int id = (bz - 2304) * 256 + t;
    const float4* s; unsigned short* d; int k;
    if (id < 16384)      { s = Wv; d = wv_bf; k = id; }
    else if (id < 81920) { s = W1; d = w1_bf; k = id - 16384; }
    else                 { s = W2; d = w2_bf; k = id - 81920; }
    float4 v = s[k];
    ushort4 o; o.x = f2bf(v.x); o.y = f2bf(v.y); o.z = f2bf(v.z); o.w = f2bf(v.w);
    *(ushort4*)&d[k * 4] = o;
  }
}

// ---------- attention GEMM: z<64 -> xv projection; z>=64 -> energy + stats ----------
__global__ __launch_bounds__(256) void attn_gemm(
    const unsigned short* __restrict__ xkt, const unsigned short* __restrict__ xqt,
    const unsigned short* __restrict__ wv, const unsigned short* __restrict__ xt,
    const float* __restrict__ bv, unsigned short* __restrict__ E,
    unsigned short* __restrict__ xv, float2* __restrict__ part) {
  __shared__ unsigned short As[128 * 32];
  __shared__ unsigned short Bs[128 * 32];
  int z = blockIdx.x;
  const unsigned short *A, *B;
  unsigned short* Co;
  long i0, j0;
  int q = 0;
  bool isXV = z < 64;
  if (isXV) {
    int b = z >> 4, r = z & 15;
    i0 = (r >> 3) * 128; j0 = (r & 7) * 128;
    A = wv; B = xt + (long)b * CN; Co = xv + (long)b * CN;
  } else {
    int ze = z - 64;
    q = ze >> 6; int r = ze & 63;
    i0 = (r >> 3) * 128; j0 = (r & 7) * 128;
    A = xkt + (long)(q & 3) * CN; B = xqt + (long)q * CN;
    Co = E + (long)q * NN * NN;
  }
  int t = threadIdx.x, w = t >> 6, l = t & 63;
  int wr = w >> 1, wc = w & 1;
  f32x4 acc[4][4];
#pragma unroll
  for (int a = 0; a < 4; ++a)
#pragma unroll
    for (int b = 0; b < 4; ++b) acc[a][b] = (f32x4){0.f, 0.f, 0.f, 0.f};
  int lr = l & 15, lk = (l >> 4) * 8;
  for (int k0 = 0; k0 < 256; k0 += 32) {
#pragma unroll
    for (int it = 0; it < 2; ++it) {
      int chunk = t + it * 256;
      int row = chunk >> 2, kq = chunk & 3;
      gload_lds16(A + (i0 + row) * 256L + k0 + kq * 8, &As[chunk * 8]);
      gload_lds16(B + (j0 + row) * 256L + k0 + kq * 8, &Bs[chunk * 8]);
    }
    __syncthreads();
    short8 af[4], bfr[4];
#pragma unroll
    for (int f = 0; f < 4; ++f) af[f]  = *(const short8*)&As[(wr * 64 + f * 16 + lr) * 32 + lk];
#pragma unroll
    for (int f = 0; f < 4; ++f) bfr[f] = *(const short8*)&Bs[(wc * 64 + f * 16 + lr) * 32 + lk];
#pragma unroll
    for (int fm = 0; fm < 4; ++fm)
#pragma unroll
      for (int fn = 0; fn < 4; ++fn)
        acc[fm][fn] = __builtin_amdgcn_mfma_f32_16x16x32_bf16(af[fm], bfr[fn], acc[fm][fn], 0, 0, 0);
    __syncthreads();
  }
  int li = (l >> 4) * 4, lj = l & 15;
#pragma unroll
  for (int fm = 0; fm < 4; ++fm)
#pragma unroll
    for (int fn = 0; fn < 4; ++fn) {
      long ib = i0 + wr * 64 + fm * 16 + li;
      long j  = j0 + wc * 64 + fn * 16 + lj;
#pragma unroll
      for (int r = 0; r < 4; ++r) {
        float v = acc[fm][fn][r];
        if (isXV) v += bv[ib + r];
        Co[(ib + r) * 1024 + j] = f2bf(v);
      }
    }
  if (!isXV) {
    int chunk = (int)(i0 >> 6) + wr;
#pragma unroll
    for (int fn = 0; fn < 4; ++fn) {
      float mx = -1e30f;
#pragma unroll
      for (int fm = 0; fm < 4; ++fm)
#pragma unroll
        for (int r = 0; r < 4; ++r) mx = fmaxf(mx, acc[fm][fn][r]);
      mx = fmaxf(mx, __shfl_xor(mx, 16));
      mx = fmaxf(mx, __shfl_xor(mx, 32));
      float sm = 0.f;
#pragma unroll
      for (int fm = 0; fm < 4; ++fm)
#pragma unroll
        for (int r = 0; r < 4; ++r) sm += __expf(acc[fm][fn][r] - mx);
      sm += __shfl_xor(sm, 16);
      sm += __shfl_xor(sm, 32);
      if (l < 16) {
        long n = j0 + wc * 64 + fn * 16 + l;
        part[((long)q * 16 + chunk) * NN + n] = make_float2(mx, sm);
      }
    }
  }
}

// ---------- bf16 MFMA GEMM, 128xBN tile (MLP shapes) ----------
template<int BN, int BIASCOL, int RELU>
__global__ __launch_bounds__(256) void mgemm(
    const unsigned short* __restrict__ A, const unsigned short* __restrict__ B,
    unsigned short* __restrict__ Cout, const float* __restrict__ bias,
    int lda, int ldb, int ldc, int K,
    long sA, int amod, long sB, int bmod, long sC) {
  __shared__ unsigned short As[128 * 32];
  __shared__ unsigned short Bs[BN * 32];
  int z = blockIdx.z;
  A += (long)(z % amod) * sA;
  B += (long)(z % bmod) * sB;
  int t = threadIdx.x, w = t >> 6, l = t & 63;
  int wr = w >> 1, wc = w & 1;
  const int WN = BN / 2, FN = BN / 32;
  long i0 = blockIdx.y * 128, j0 = blockIdx.x * BN;
  f32x4 acc[4][FN];
#pragma unroll
  for (int a = 0; a < 4; ++a)
#pragma unroll
    for (int b = 0; b < FN; ++b) acc[a][b] = (f32x4){0.f, 0.f, 0.f, 0.f};
  int lr = l & 15, lk = (l >> 4) * 8;
  for (int k0 = 0; k0 < K; k0 += 32) {
#pragma unroll
    for (int it = 0; it < 2; ++it) {
      int chunk = t + it * 256;
      int row = chunk >> 2, kq = chunk & 3;
      gload_lds16(A + (i0 + row) * (long)lda + k0 + kq * 8, &As[chunk * 8]);
    }
#pragma unroll
    for (int it = 0; it < BN / 64; ++it) {
      int chunk = t + it * 256;
      int row = chunk >> 2, kq = chunk & 3;
      gload_lds16(B + (j0 + row) * (long)ldb + k0 + kq * 8, &Bs[chunk * 8]);
    }
    __syncthreads();
    short8 af[4], bfr[FN];
#pragma unroll
    for (int f = 0; f < 4; ++f)  af[f]  = *(const short8*)&As[(wr * 64 + f * 16 + lr) * 32 + lk];
#pragma unroll
    for (int f = 0; f < FN; ++f) bfr[f] = *(const short8*)&Bs[(wc * WN + f * 16 + lr) * 32 + lk];
#pragma unroll
    for (int fm = 0; fm < 4; ++fm)
#pragma unroll
      for (int fn = 0; fn < FN; ++fn)
        acc[fm][fn] = __builtin_amdgcn_mfma_f32_16x16x32_bf16(af[fm], bfr[fn], acc[fm][fn], 0, 0, 0);
    __syncthreads();
  }
  long cz = (long)z * sC;
  int li = (l >> 4) * 4, lj = l & 15;
#pragma unroll
  for (int fm = 0; fm < 4; ++fm)
#pragma unroll
    for (int fn = 0; fn < FN; ++fn) {
      long ib = i0 + wr * 64 + fm * 16 + li;
      long j  = j0 + wc * WN + fn * 16 + lj;
#pragma unroll
      for (int r = 0; r < 4; ++r) {
        float v = acc[fm][fn][r];
        if (BIASCOL) v += bias[j];
        if (RELU)    v = fmaxf(v, 0.f);
        Cout[cz + (ib + r) * ldc + j] = f2bf(v);
      }
    }
}

// ---------- PV GEMM, K-split x4, fused stat-combine + exp; bf16 partials ----------
__global__ __launch_bounds__(256) void pv_gemm(
    const unsigned short* __restrict__ E, const unsigned short* __restrict__ XV,
    const float2* __restrict__ part, unsigned short* __restrict__ xrp) {
  __shared__ unsigned short As[128 * 32];
  __shared__ unsigned short Bs[128 * 32];
  __shared__ float Ms[256];
  __shared__ float Ds[256];
  int z = blockIdx.z;
  int q = z >> 2, s = z & 3;
  const unsigned short* A = E + (long)q * NN * NN + s * 256;
  const unsigned short* B = XV + (long)(q & 3) * CN + s * 256;
  int t = threadIdx.x;
  {
    int n = s * 256 + t;
    float mx = -1e30f;
#pragma unroll
    for (int c = 0; c < 16; ++c) mx = fmaxf(mx, part[((long)q * 16 + c) * NN + n].x);
    float sm = 0.f;
#pragma unroll
    for (int c = 0; c < 16; ++c) {
      float2 p = part[((long)q * 16 + c) * NN + n];
      sm += p.y * __expf(p.x - mx);
    }
    Ms[t] = mx;
    Ds[t] = 1.f / sm;
  }
  int w = t >> 6, l = t & 63;
  int wr = w >> 1, wc = w & 1;
  long i0 = blockIdx.y * 128, j0 = blockIdx.x * 128;
  f32x4 acc[4][4];
#pragma unroll
  for (int a = 0; a < 4; ++a)
#pragma unroll
    for (int b = 0; b < 4; ++b) acc[a][b] = (f32x4){0.f, 0.f, 0.f, 0.f};
  int lr = l & 15, lk = (l >> 4) * 8;
  int ar = t >> 1, ah = (t & 1) * 16;
  __syncthreads();
  for (int k0 = 0; k0 < 256; k0 += 32) {
#pragma unroll
    for (int it = 0; it < 2; ++it) {
      int chunk = t + it * 256;
      int row = chunk >> 2, kq = chunk & 3;
      gload_lds16(B + (j0 + row) * 1024L + k0 + kq * 8, &Bs[chunk * 8]);
    }
    u16x8 e0 = *(const u16x8*)&A[(i0 + ar) * 1024L + k0 + ah];
    u16x8 e1 = *(const u16x8*)&A[(i0 + ar) * 1024L + k0 + ah + 8];
    u16x8 p0, p1;
#pragma unroll
    for (int j = 0; j < 8; ++j) {
      int n = k0 + ah + j;
      p0[j] = f2bf(__expf(bf2f(e0[j]) - Ms[n]) * Ds[n]);
    }
#pragma unroll
    for (int j = 0; j < 8; ++j) {
      int n = k0 + ah + 8 + j;
      p1[j] = f2bf(__expf(bf2f(e1[j]) - Ms[n]) * Ds[n]);
    }
    *(u16x8*)&As[ar * 32 + ah]     = p0;
    *(u16x8*)&As[ar * 32 + ah + 8] = p1;
    __syncthreads();
    short8 af[4], bfr[4];
#pragma unroll
    for (int f = 0; f < 4; ++f) af[f]  = *(const short8*)&As[(wr * 64 + f * 16 + lr) * 32 + lk];
#pragma unroll
    for (int f = 0; f < 4; ++f) bfr[f] = *(const short8*)&Bs[(wc * 64 + f * 16 + lr) * 32 + lk];
#pragma unroll
    for (int fm = 0; fm < 4; ++fm)
#pragma unroll
      for (int fn = 0; fn < 4; ++fn)
        acc[fm][fn] = __builtin_amdgcn_mfma_f32_16x16x32_bf16(af[fm], bfr[fn], acc[fm][fn], 0, 0, 0);
    __syncthreads();
  }
  long cz = (long)(s * 12 + q) << 18;
  int li = (l >> 4) * 4, lj = l & 15;
#pragma unroll
  for (int fm = 0; fm < 4; ++fm)
#pragma unroll
    for (int fn = 0; fn < 4; ++fn) {
      long ib = i0 + wr * 64 + fm * 16 + li;
      long j  = j0 + wc * 64 + fn * 16 + lj;
#pragma unroll
      for (int r = 0; r < 4; ++r)
        xrp[cz + (ib + r) * 256 + j] = f2bf(acc[fm][fn][r] * (1.f / 16.f));
    }
}

// ---------- mix (reshape-mean over 12 bf16 partials) + residual + LN1 ----------
__global__ __launch_bounds__(256) void mix_ln1(
    const unsigned short* __restrict__ xT, const unsigned short* __restrict__ xrp,
    const float* __restrict__ g, const float* __restrict__ bb,
    unsigned short* __restrict__ h_bf) {
  __shared__ float r1[4], r2[4];
  int bn = blockIdx.x;
  int i = bn >> 10, n = bn & 1023;
  int c = threadIdx.x;
  long no = (long)n * CC + c;
  float a = 0.f;
#pragma unroll
  for (int j = 0; j < 3; ++j)
#pragma unroll
    for (int s = 0; s < 4; ++s)
      a += bf2f(xrp[((long)(s * 12 + 3 * i + j) << 18) + no]);
  float v = bf2f(xT[(long)i * CN + no]) + a * (1.f / 3.f);
  float sS = v, s2 = v * v;
#pragma unroll
  for (int m = 32; m; m >>= 1) { sS += __shfl_xor(sS, m); s2 += __shfl_xor(s2, m); }
  if ((c & 63) == 0) { r1[c >> 6] = sS; r2[c >> 6] = s2; }
  __syncthreads();
  float mu = (r1[0] + r1[1] + r1[2] + r1[3]) * (1.f / 256.f);
  float var = (r2[0] + r2[1] + r2[2] + r2[3]) * (1.f / 256.f) - mu * mu;
  float o = (v - mu) * rsqrtf(var + 1e-6f) * g[c] + bb[c];
  h_bf[(long)bn * CC + c] = f2bf(o);
}

// ---------- combine MLP2 bf16 partials + bias + residual + LN2 + relu + transpose ----------
__global__ __launch_bounds__(256) void ln2t(
    const unsigned short* __restrict__ pm, const unsigned short* __restrict__ h_bf,
    const float* __restrict__ b2, const float* __restrict__ g,
    const float* __restrict__ bb, float* __restrict__ out) {
  __shared__ float tile[16][261];
  __shared__ float smu[16], srs[16];
  int i = blockIdx.y, n0 = blockIdx.x * 16;
  int t = threadIdx.x;
  float bc = b2[t];
#pragma unroll
  for (int r = 0; r < 16; ++r) {
    long row = (long)i * NN + n0 + r;
    float v = bc + bf2f(h_bf[row * CC + t]);
#pragma unroll
    for (int s = 0; s < 4; ++s) v += bf2f(pm[((long)s << 20) + row * CC + t]);
    tile[r][t] = v;
  }
  __syncthreads();
  int w = t >> 6, l = t & 63;
#pragma unroll
  for (int rr = 0; rr < 4; ++rr) {
    int r = w * 4 + rr;
    float s = 0.f, s2 = 0.f;
#pragma unroll
    for (int k = 0; k < 4; ++k) { float v = tile[r][l + 64 * k]; s += v; s2 += v * v; }
#pragma unroll
    for (int m = 32; m; m >>= 1) { s += __shfl_xor(s, m); s2 += __shfl_xor(s2, m); }
    if (l == 0) {
      float mu = s * (1.f / 256.f);
      float var = s2 * (1.f / 256.f) - mu * mu;
      smu[r] = mu; srs[r] = rsqrtf(var + 1e-6f);
    }
  }
  __syncthreads();
#pragma unroll
  for (int k = 0; k < 16; ++k) {
    int nn = t & 15, c = (t >> 4) + 16 * k;
    float v = (tile[nn][c] - smu[nn]) * srs[nn] * g[c] + bb[c];
    out[((long)i * CC + c) * NN + n0 + nn] = fmaxf(v, 0.f);
  }
}

extern "C" void kernel_launch(void* const* d_in, const int* in_sizes, int n_in,
                              void* d_out, int out_size, void* d_ws, size_t ws_size,
                              hipStream_t stream) {
  const float* x   = (const float*)d_in[0];
  const float* Wq  = (const float*)d_in[1];
  const float* Wk  = (const float*)d_in[2];
  const float* Wv  = (const float*)d_in[3];
  const float* bv  = (const float*)d_in[4];
  const float* g1  = (const float*)d_in[5];
  const float* b1v = (const float*)d_in[6];
  const float* W1  = (const float*)d_in[7];
  const float* b1m = (const float*)d_in[8];
  const float* W2  = (const float*)d_in[9];
  const float* b2m = (const float*)d_in[10];
  const float* g2  = (const float*)d_in[11];
  const float* b2v = (const float*)d_in[12];
  float* out = (float*)d_out;

  char* base = (char*)d_ws;
  // [0,24MB): E_bf; reused after pv: h_bf [0,2), hid_bf [2,10)
  unsigned short* E_bf   = (unsigned short*)base;
  unsigned short* h_bf   = (unsigned short*)base;
  unsigned short* hid_bf = (unsigned short*)(base + (2u << 20));
  size_t off = 24u << 20;
  unsigned short* xrp    = (unsigned short*)(base + off); off += 25165824;  // 24MB
  unsigned short* p_mlp  = (unsigned short*)(base + off); off += 8388608;   // 8MB
  unsigned short* wv_bf  = (unsigned short*)(base + off); off += 131072;
  unsigned short* w1_bf  = (unsigned short*)(base + off); off += 524288;
  unsigned short* w2_bf  = (unsigned short*)(base + off); off += 524288;
  unsigned short* xt_bf  = (unsigned short*)(base + off); off += 2097152;
  unsigned short* xqt_bf = (unsigned short*)(base + off); off += 6291456;
  unsigned short* xkt_bf = (unsigned short*)(base + off); off += 2097152;
  unsigned short* xv_bf  = (unsigned short*)(base + off); off += 2097152;
  float2* part           = (float2*)(base + off);         off += 1572864;

  // 1. prep: q/k proj + passthrough (2048) + x-transpose (256) + convert (576)
  prep_kernel<<<2880, 256, 0, stream>>>(x, Wq, Wk, (const float4*)Wv,
      (const float4*)W1, (const float4*)W2, wv_bf, w1_bf, w2_bf,
      xt_bf, xqt_bf, xkt_bf, out);
  // 2. attention GEMMs: xv (64 blocks) + energy/stats (768 blocks)
  attn_gemm<<<832, 256, 0, stream>>>(xkt_bf, xqt_bf, wv_bf, xt_bf,
      bv, E_bf, xv_bf, part);
  // 3. PV (K-split x4) with fused stat-combine + exp -> xrp bf16
  pv_gemm<<<dim3(2, 8, 48), 256, 0, stream>>>(E_bf, xv_bf, part, xrp);
  // 4. mix + LN1 -> h_bf
  mix_ln1<<<4096, 256, 0, stream>>>(xt_bf, xrp, g1, b1v, h_bf);
  // 5. hid = relu(h @ W1^T + b1) -> bf16, 128x64 tiles (512 blocks)
  mgemm<64,1,1><<<dim3(16, 32, 1), 256, 0, stream>>>(
      h_bf, w1_bf, hid_bf, b1m,
      256, 256, 1024, 256, 0L, 1, 0L, 1, 0L);
  // 6. MLP2 partials (K-split x4), 128x64 tiles (512 blocks) -> bf16
  mgemm<64,0,0><<<dim3(4, 32, 4), 256, 0, stream>>>(
      hid_bf, w2_bf, p_mlp, nullptr,
      1024, 1024, 256, 256, 256L, 4, 256L, 4, 1048576L);
  // 7. combine + bias + residual + LN2 + relu + transpose -> out[0..3]
  ln2t<<<dim3(64, 4), 256, 0, stream>>>(p_mlp, h_bf, b2m, g2, b2v, out);
}